// Round 8
// baseline (217.027 us; speedup 1.0000x reference)
//
#include <hip/hip_runtime.h>
#include <hip/hip_fp16.h>

// Problem constants: B=4, S=1024, HID=1024, NH=16, HD=64
#define B_    4
#define S_    1024
#define HID_  1024
#define NH_   16
#define HD_   64

#define LOG2E 1.44269504f
#define PSTR  36   // padded LDS row stride in halves (72 B = 18 dwords):
                   // (18*l15 + 4*quad) % 32 -> uniform 2-way bank aliasing (free)

typedef _Float16 half8 __attribute__((ext_vector_type(8)));
typedef _Float16 half4v __attribute__((ext_vector_type(4)));
typedef float f32x4 __attribute__((ext_vector_type(4)));

// ---------------------------------------------------------------------------
// pack4: four fp32 arrays -> fp16 row-major (blockIdx.y selects array)
// ---------------------------------------------------------------------------
__global__ __launch_bounds__(256) void pack4(
    const float* __restrict__ s0, _Float16* __restrict__ d0, int n40,
    const float* __restrict__ s1, _Float16* __restrict__ d1, int n41,
    const float* __restrict__ s2, _Float16* __restrict__ d2, int n42,
    const float* __restrict__ s3, _Float16* __restrict__ d3, int n43)
{
    int y = blockIdx.y;
    const float* s = y == 0 ? s0 : y == 1 ? s1 : y == 2 ? s2 : s3;
    _Float16*    d = y == 0 ? d0 : y == 1 ? d1 : y == 2 ? d2 : d3;
    int n4         = y == 0 ? n40 : y == 1 ? n41 : y == 2 ? n42 : n43;
    int i = blockIdx.x * 256 + threadIdx.x;
    if (i >= n4) return;
    float4 v = ((const float4*)s)[i];
    half4v h;
    h[0] = (_Float16)v.x; h[1] = (_Float16)v.y;
    h[2] = (_Float16)v.z; h[3] = (_Float16)v.w;
    ((half4v*)d)[i] = h;
}

// ---------------------------------------------------------------------------
// Fused q/k projection (z: 0=q, 1=k).  Reads fp16 A/W (pre-packed), stages
// into LDS with PSTR padding (2-way bank aliasing = free).
// out = A @ W^T + bias written in MFMA-fragment-friendly layouts:
//   Q' : [b, h, qtile=s/16, kplane=d/8, s%16, d%8]   (wave A-load = 1KB dense)
//   K' : [b, h, kplane=d/8, s, d%8]                  (wave B-load = 4x256B)
// 128x128 tile, 512 thr = 8 waves (2m x 4n), BK=32.
// ---------------------------------------------------------------------------
__global__ __launch_bounds__(512) void proj_qk_f16(
    const _Float16* __restrict__ qh_, const _Float16* __restrict__ Wqh,
    const float* __restrict__ bq, _Float16* __restrict__ Oq,
    const _Float16* __restrict__ kh_, const _Float16* __restrict__ Wkh,
    const float* __restrict__ bk, _Float16* __restrict__ Ok)
{
    const _Float16* A  = blockIdx.z ? kh_ : qh_;
    const _Float16* Wm = blockIdx.z ? Wkh : Wqh;
    const float* bias  = blockIdx.z ? bk  : bq;
    _Float16* Co       = blockIdx.z ? Ok  : Oq;

    __shared__ _Float16 Al[128 * PSTR];   // 9 KB
    __shared__ _Float16 Bl[128 * PSTR];

    const int tid  = threadIdx.x;
    const int wv   = tid >> 6;
    const int lane = tid & 63;
    const int l15  = lane & 15;
    const int quad = lane >> 4;
    const int wm   = wv & 1, wn = wv >> 1;            // wn 0..3
    const int m0   = blockIdx.y * 128, n0 = blockIdx.x * 128;
    const int sr   = tid >> 2;                        // 0..127
    const int sc   = (tid & 3) * 8;                   // halves (16B chunks)

    f32x4 acc[4][2];
#pragma unroll
    for (int i = 0; i < 4; i++)
#pragma unroll
        for (int j = 0; j < 2; j++) acc[i][j] = (f32x4){0.f, 0.f, 0.f, 0.f};

    for (int kt = 0; kt < HID_; kt += 32) {
        half8 av = *(const half8*)(A  + (long)(m0 + sr) * HID_ + kt + sc);
        half8 bv = *(const half8*)(Wm + (long)(n0 + sr) * HID_ + kt + sc);
        __syncthreads();   // previous iter's frag reads complete
        *(half8*)(Al + sr * PSTR + sc) = av;
        *(half8*)(Bl + sr * PSTR + sc) = bv;
        __syncthreads();

        half8 af[4], bfm[2];
#pragma unroll
        for (int i = 0; i < 4; i++)
            af[i] = *(const half8*)(Al + (wm * 64 + i * 16 + l15) * PSTR + quad * 8);
#pragma unroll
        for (int j = 0; j < 2; j++)
            bfm[j] = *(const half8*)(Bl + (wn * 32 + j * 16 + l15) * PSTR + quad * 8);
#pragma unroll
        for (int i = 0; i < 4; i++)
#pragma unroll
            for (int j = 0; j < 2; j++)
                acc[i][j] = __builtin_amdgcn_mfma_f32_16x16x32_f16(
                    af[i], bfm[j], acc[i][j], 0, 0, 0);
    }

    const int isQ = (blockIdx.z == 0);
#pragma unroll
    for (int j = 0; j < 2; j++) {
        int col = n0 + wn * 32 + j * 16 + l15;
        float bv = bias[col];
        int h = col >> 6, d = col & 63, p = d >> 3, jj = d & 7;
#pragma unroll
        for (int i = 0; i < 4; i++) {
            int row = m0 + wm * 64 + i * 16 + quad * 4;
            int bb = row >> 10, ss = row & 1023;   // tiles never straddle 1024
            long base;
            if (isQ)
                base = ((((long)(bb * NH_ + h) * 64 + (ss >> 4)) * 8 + p) * 16
                        + (ss & 15)) * 8 + jj;
            else
                base = (((long)(bb * NH_ + h) * 8 + p) * 1024 + ss) * 8 + jj;
            // both layouts advance by 8 elements per +1 row
#pragma unroll
            for (int r = 0; r < 4; r++)
                Co[base + r * 8] = (_Float16)(acc[i][j][r] + bv);
        }
    }
}

// ---------------------------------------------------------------------------
// MFMA attention, head-split z=4.  Fragment loads from the dense Q'/K'
// layouts: A-load = 1KB contiguous per wave, B-load = 4x256B segments.
// No-max softmax (scores bounded, exp2 + folded log2e), ONE barrier per head.
// ---------------------------------------------------------------------------
__global__ __launch_bounds__(512) void attn_psum_f16(
    const _Float16* __restrict__ qb,   // Q' [B,NH,64,8,16,8]
    const _Float16* __restrict__ kb,   // K' [B,NH,8,S,8]
    const float* __restrict__ mask,    // [B,S]
    _Float16* __restrict__ P)          // 4 x [B,S,S] fp16 quarters
{
    const int b    = blockIdx.y;
    const int qt   = blockIdx.x;       // q-tile (16 rows)
    const int q0   = qt * 16;
    const int hz   = blockIdx.z;       // head group 0..3
    const int tid  = threadIdx.x;
    const int w    = tid >> 6;         // wave 0..7
    const int lane = tid & 63;
    const int l15  = lane & 15;
    const int quad = lane >> 4;

    __shared__ float redS[2][16][8];

    const float SC = 0.125f * LOG2E;

    float mreg[8];
#pragma unroll
    for (int t = 0; t < 8; t++)
        mreg[t] = mask[b * S_ + t * 128 + w * 16 + l15] * LOG2E;

    f32x4 acc[8];
#pragma unroll
    for (int t = 0; t < 8; t++) acc[t] = (f32x4){0.f, 0.f, 0.f, 0.f};

    for (int ii = 0; ii < 4; ii++) {
        const int h = hz * 4 + ii;
        const _Float16* qh = qb + ((long)(b * NH_ + h) * 64 + qt) * 1024;
        const _Float16* kh = kb + (long)(b * NH_ + h) * 8192 * 8;

        // A frags: Q'[qt][plane=quad(+4)][l15][j] — dense wave loads
        half8 a0 = *(const half8*)(qh + quad * 128 + l15 * 8);
        half8 a1 = *(const half8*)(qh + (quad + 4) * 128 + l15 * 8);

        f32x4 s[8];
#pragma unroll
        for (int cc = 0; cc < 8; cc++) {
            const int key = cc * 128 + w * 16 + l15;
            half8 b0 = *(const half8*)(kh + (long)quad * 8192 + key * 8);
            half8 b1 = *(const half8*)(kh + (long)(quad + 4) * 8192 + key * 8);
            f32x4 c = (f32x4){0.f, 0.f, 0.f, 0.f};
            c = __builtin_amdgcn_mfma_f32_16x16x32_f16(a0, b0, c, 0, 0, 0);
            c = __builtin_amdgcn_mfma_f32_16x16x32_f16(a1, b1, c, 0, 0, 0);
            s[cc] = c;
        }

        // ---- exp2 + row-sum (no max pass; one barrier per head) ----
        const int p = ii & 1;
        float sm[4] = {0.f, 0.f, 0.f, 0.f};
#pragma unroll
        for (int t = 0; t < 8; t++)
#pragma unroll
            for (int r = 0; r < 4; r++) {
                float pr = exp2f(s[t][r] * SC + mreg[t]);
                s[t][r] = pr;
                sm[r] += pr;
            }
#pragma unroll
        for (int off = 1; off < 16; off <<= 1)
#pragma unroll
            for (int r = 0; r < 4; r++) sm[r] += __shfl_xor(sm[r], off);
        if (l15 == 0)
#pragma unroll
            for (int r = 0; r < 4; r++) redS[p][quad * 4 + r][w] = sm[r];
        __syncthreads();

#pragma unroll
        for (int r = 0; r < 4; r++) {
            float4 v0 = *(float4*)&redS[p][quad * 4 + r][0];
            float4 v1 = *(float4*)&redS[p][quad * 4 + r][4];
            float tot = (v0.x + v0.y + v0.z + v0.w) + (v1.x + v1.y + v1.z + v1.w);
            float inv = 1.f / tot;
#pragma unroll
            for (int t = 0; t < 8; t++) acc[t][r] += s[t][r] * inv;
        }
    }

    _Float16* prow = P + (long)hz * ((long)B_ * S_ * S_) + (long)(b * S_ + q0) * S_;
#pragma unroll
    for (int t = 0; t < 8; t++)
#pragma unroll
        for (int r = 0; r < 4; r++) {
            int row = quad * 4 + r;
            prow[(long)row * S_ + t * 128 + w * 16 + l15] = (_Float16)acc[t][r];
        }
}

// ---------------------------------------------------------------------------
// vt_combine: y==0 -> psum = P0+P1+P2+P3 (2048 x-blocks)
//             y==1 -> Vt[b,h,s] = (fp16) V[b,s,h]  (4096 x-blocks)
// Runs after attn: reads Pq[16,48M) & V; writes psum[8,16M), Vt[0,8M).
// ---------------------------------------------------------------------------
__global__ __launch_bounds__(256) void vt_combine(
    const _Float16* __restrict__ P, _Float16* __restrict__ o,
    const float* __restrict__ V, _Float16* __restrict__ Vt)
{
    __shared__ float t[32][33];
    if (blockIdx.y == 0) {
        if (blockIdx.x >= 2048) return;
        const long QS = (long)B_ * S_ * S_;
        long i = (long)(blockIdx.x * 256 + threadIdx.x) * 8;
        half8 a = *(const half8*)(P + i);
        half8 b = *(const half8*)(P + QS + i);
        half8 c = *(const half8*)(P + 2 * QS + i);
        half8 d = *(const half8*)(P + 3 * QS + i);
        half8 r;
#pragma unroll
        for (int e = 0; e < 8; e++)
            r[e] = (_Float16)((float)a[e] + (float)b[e] + (float)c[e] + (float)d[e]);
        *(half8*)(o + i) = r;
    } else {
        const int x  = blockIdx.x;
        const int b  = x >> 10;
        const int s0 = ((x >> 5) & 31) * 32;
        const int h0 = (x & 31) * 32;
        const int tx = threadIdx.x & 31, ty = threadIdx.x >> 5;
#pragma unroll
        for (int rr = 0; rr < 4; rr++) {
            int s = s0 + ty + rr * 8;
            t[ty + rr * 8][tx] = V[((long)b * S_ + s) * HID_ + h0 + tx];
        }
        __syncthreads();
#pragma unroll
        for (int rr = 0; rr < 4; rr++) {
            int h = h0 + ty + rr * 8;
            Vt[((long)b * HID_ + h) * S_ + s0 + tx] = (_Float16)t[tx][ty + rr * 8];
        }
    }
}

// ---------------------------------------------------------------------------
// PV GEMM: out = (psum @ Vt^T) / NH, fp16 MFMA, fp32 out.  Batched z=b.
// 128m x 64n tile, 256 thr = 4 waves (2m x 2n), BK=32, padded LDS staging.
// ---------------------------------------------------------------------------
__global__ __launch_bounds__(256) void pv_f16(
    const _Float16* __restrict__ Pc,   // [B,S,S] fp16
    const _Float16* __restrict__ Vt,   // [B,HID,S] fp16
    float* __restrict__ out)           // [B,S,HID] fp32
{
    const int b = blockIdx.z;
    const _Float16* A  = Pc + (long)b * S_ * S_;
    const _Float16* Bm = Vt + (long)b * HID_ * S_;

    __shared__ _Float16 Al[128 * PSTR];  // 9 KB
    __shared__ _Float16 Bl[64 * PSTR];   // 4.5 KB

    const int tid  = threadIdx.x;
    const int wv   = tid >> 6;
    const int lane = tid & 63;
    const int l15  = lane & 15;
    const int quad = lane >> 4;
    const int wm   = wv & 1, wn = wv >> 1;
    const int m0   = blockIdx.y * 128, n0 = blockIdx.x * 64;
    const int sr   = tid >> 2;                       // 0..63
    const int sc   = (tid & 3) * 8;

    f32x4 acc[4][2];
#pragma unroll
    for (int i = 0; i < 4; i++)
#pragma unroll
        for (int j = 0; j < 2; j++) acc[i][j] = (f32x4){0.f, 0.f, 0.f, 0.f};

    for (int kt = 0; kt < S_; kt += 32) {
        half8 a0 = *(const half8*)(A  + (long)(m0 + sr) * S_ + kt + sc);
        half8 a1 = *(const half8*)(A  + (long)(m0 + 64 + sr) * S_ + kt + sc);
        half8 b0 = *(const half8*)(Bm + (long)(n0 + sr) * S_ + kt + sc);
        __syncthreads();
        *(half8*)(Al + sr * PSTR + sc) = a0;
        *(half8*)(Al + (64 + sr) * PSTR + sc) = a1;
        *(half8*)(Bl + sr * PSTR + sc) = b0;
        __syncthreads();

        half8 af[4], bfm[2];
#pragma unroll
        for (int i = 0; i < 4; i++)
            af[i] = *(const half8*)(Al + (wm * 64 + i * 16 + l15) * PSTR + quad * 8);
#pragma unroll
        for (int j = 0; j < 2; j++)
            bfm[j] = *(const half8*)(Bl + (wn * 32 + j * 16 + l15) * PSTR + quad * 8);
#pragma unroll
        for (int i = 0; i < 4; i++)
#pragma unroll
            for (int j = 0; j < 2; j++)
                acc[i][j] = __builtin_amdgcn_mfma_f32_16x16x32_f16(
                    af[i], bfm[j], acc[i][j], 0, 0, 0);
    }

    const float alpha = 1.f / NH_;
#pragma unroll
    for (int i = 0; i < 4; i++) {
        int row = m0 + wm * 64 + i * 16 + quad * 4;
#pragma unroll
        for (int j = 0; j < 2; j++) {
            int col = n0 + wn * 32 + j * 16 + l15;
#pragma unroll
            for (int r = 0; r < 4; r++)
                out[(long)(b * S_ + row + r) * HID_ + col] = acc[i][j][r] * alpha;
        }
    }
}

// ---------------------------------------------------------------------------
extern "C" void kernel_launch(void* const* d_in, const int* in_sizes, int n_in,
                              void* d_out, int out_size, void* d_ws, size_t ws_size,
                              hipStream_t stream)
{
    const float* mask  = (const float*)d_in[0];
    const float* query = (const float*)d_in[1];
    const float* key   = (const float*)d_in[2];
    const float* value = (const float*)d_in[3];
    const float* Wq    = (const float*)d_in[4];
    const float* bq    = (const float*)d_in[5];
    const float* Wk    = (const float*)d_in[6];
    const float* bk    = (const float*)d_in[7];
    float* out = (float*)d_out;

    // Workspace (48 MiB, hand-offs between SEQUENTIAL dispatches only):
    //  [ 0, 8M): Q' (proj out)        -> after attn: Vt
    //  [ 8,16M): K' (proj out)        -> after attn: psum (combine out)
    //  [16,24M): qh fp16              -> after proj: P0
    //  [24,32M): kh fp16              -> after proj: P1
    //  [32,34M): Wqh ; [34,36M): Wkh  -> after proj: P2 head
    //  [16,48M): P quarters (4 x 8M) written by attn
    char* ws = (char*)d_ws;
    const long MB = 1l << 20;
    _Float16* qbuf = (_Float16*)(ws);
    _Float16* kbuf = (_Float16*)(ws + 8 * MB);
    _Float16* qh   = (_Float16*)(ws + 16 * MB);
    _Float16* kh   = (_Float16*)(ws + 24 * MB);
    _Float16* Wqh  = (_Float16*)(ws + 32 * MB);
    _Float16* Wkh  = (_Float16*)(ws + 34 * MB);
    _Float16* Pq   = (_Float16*)(ws + 16 * MB);
    _Float16* Vt   = (_Float16*)(ws);             // reuses Q' after attn
    _Float16* psum = (_Float16*)(ws + 8 * MB);    // reuses K' after attn

    const int nQK = (B_ * S_ * HID_) / 4;   // 1M float4
    const int nW  = (HID_ * HID_) / 4;      // 256K float4

    // 1) fp32 -> fp16 packs (query, key, Wq, Wk)
    pack4<<<dim3(nQK / 256, 4), dim3(256), 0, stream>>>(
        query, qh, nQK, key, kh, nQK, Wq, Wqh, nW, Wk, Wkh, nW);

    // 2) fused q/k projection (fp16 in, fragment-layout fp16 out)
    proj_qk_f16<<<dim3(HID_ / 128, (B_ * S_) / 128, 2), dim3(512), 0, stream>>>(
        qh, Wqh, bq, qbuf, kh, Wkh, bk, kbuf);

    // 3) attention, head-split z=4 -> psum quarters
    attn_psum_f16<<<dim3(S_ / 16, B_, 4), dim3(512), 0, stream>>>(
        qbuf, kbuf, mask, Pq);

    // 4) fused: sum the 4 quarters -> psum ; V -> fp16 transpose -> Vt
    vt_combine<<<dim3(4096, 2), dim3(256), 0, stream>>>(Pq, psum, value, Vt);

    // 5) out = psum @ V / NH
    pv_f16<<<dim3(HID_ / 64, S_ / 128, B_), dim3(256), 0, stream>>>(psum, Vt, out);
}